// Round 19
// baseline (28.618 us; speedup 1.0000x reference)
//
#include <hip/hip_runtime.h>
#include <hip/hip_fp16.h>
#include <math.h>

#define TPB 256
#define NODES 16
#define BLOCKS 2048

typedef float f32x4 __attribute__((ext_vector_type(4)));
typedef _Float16 half4 __attribute__((ext_vector_type(4)));
typedef _Float16 half8 __attribute__((ext_vector_type(8)));
typedef _Float16 h2 __attribute__((ext_vector_type(2)));

#define LOG2E 1.44269504088896340736f
#define LN2   0.69314718055994530942f

__device__ __forceinline__ _Float16 hx2(_Float16 x) {
    __half h = __builtin_bit_cast(__half, x);
    __half r = hexp2(h);
    return __builtin_bit_cast(_Float16, r);
}

// packed f16 softplus in log2 domain, 2 values per call, 3-FMA form.
__device__ __forceinline__ unsigned int sp2_pos(float v0, float v1) {
    h2 h = __builtin_bit_cast(h2, __builtin_amdgcn_cvt_pkrtz(v0, v1));
    h2 e = { hx2((_Float16)(-h[0])), hx2((_Float16)(-h[1])) };
    const h2 c3 = {(_Float16)0.154358f,  (_Float16)0.154358f};
    const h2 c2 = {(_Float16)-0.571177f, (_Float16)-0.571177f};
    const h2 c1 = {(_Float16)1.416467f,  (_Float16)1.416467f};
    h2 q = __builtin_elementwise_fma(e, __builtin_elementwise_fma(e, c3, c2), c1);
    h2 r = __builtin_elementwise_fma(e, q, h);
    return __builtin_bit_cast(unsigned int, r);
}
__device__ __forceinline__ unsigned int sp2_any(float v0, float v1) {
    h2 h = __builtin_bit_cast(h2, __builtin_amdgcn_cvt_pkrtz(v0, v1));
    const h2 z = {(_Float16)0.0f, (_Float16)0.0f};
    h2 m  = __builtin_elementwise_max(h, z);
    h2 nt = __builtin_elementwise_min(h, -h);   // -|t|
    h2 e = { hx2(nt[0]), hx2(nt[1]) };
    const h2 c3 = {(_Float16)0.154358f,  (_Float16)0.154358f};
    const h2 c2 = {(_Float16)-0.571177f, (_Float16)-0.571177f};
    const h2 c1 = {(_Float16)1.416467f,  (_Float16)1.416467f};
    h2 q = __builtin_elementwise_fma(e, __builtin_elementwise_fma(e, c3, c2), c1);
    h2 r = __builtin_elementwise_fma(e, q, m);
    return __builtin_bit_cast(unsigned int, r);
}
__device__ __forceinline__ unsigned int pk2(float a, float b) {
    return __builtin_bit_cast(unsigned int, __builtin_amdgcn_cvt_pkrtz(a, b));
}
__device__ __forceinline__ half4 h4(uint2 u) {
    return __builtin_bit_cast(half4, u);
}
__device__ __forceinline__ half8 h8(uint2 lo, uint2 hi) {
    uint4 u; u.x = lo.x; u.y = lo.y; u.z = hi.x; u.w = hi.y;
    return __builtin_bit_cast(half8, u);
}

__global__ __launch_bounds__(TPB, 4) void mlp_mfma_kernel(
    const float* __restrict__ Fs,
    const float* __restrict__ W1, const float* __restrict__ b1,
    const float* __restrict__ W2, const float* __restrict__ b2,
    const float* __restrict__ W3, const float* __restrict__ b3,
    const float* __restrict__ W4, const float* __restrict__ b4,
    float* __restrict__ out, int n, int iters)
{
    __shared__ uint2 lds[4][320];        // per-wave: 64 samples x 5 uint2
    const int tid = threadIdx.x;
    const int l = tid & 63, w = tid >> 6;
    const int g = l >> 4, c = l & 15;

    // ---- one-time fragments/biases; no weight loads in the loop ----
    half8 a1;
    half4 a2, a3, a4;
    f32x4 cb1, cb2, cb3;
    #pragma unroll
    for (int j = 0; j < 4; ++j) {
        a1[j]   = (_Float16)(W1[(4*g+j)*NODES + c] * LOG2E);
        a1[4+j] = (_Float16)((g == 0 && j < 3) ? W1[(16+j)*NODES + c] * LOG2E : 0.0f);
        a2[j]   = (_Float16)W2[(4*g+j)*NODES + c];
        a3[j]   = (_Float16)W3[(4*g+j)*NODES + c];
        a4[j]   = (_Float16)(W4[4*g+j] * LN2);
    }
    const float b4s = b4[0];
    #pragma unroll
    for (int i = 0; i < 4; ++i) {
        cb1[i] = b1[4*g+i] * LOG2E;
        cb2[i] = b2[4*g+i] * LOG2E;
        cb3[i] = b3[4*g+i] * LOG2E;
    }
    const f32x4 zero4 = {0.0f, 0.0f, 0.0f, 0.0f};

    uint2* basep = &lds[w][0];
    const long long s0 = ((long long)blockIdx.x * 4 + w) * (64LL * iters);
    if (s0 >= n) return;

    float fr[9];
    {
        long long sE = s0 + l; if (sE > n - 1) sE = n - 1;
        const float* fp = Fs + sE * 9;
        #pragma unroll
        for (int q = 0; q < 9; ++q) fr[q] = fp[q];
    }

    for (int it = 0; it < iters; ++it) {
        long long ws = s0 + (long long)it * 64;
        if (ws >= n) break;

        float a = fr[0], b = fr[1], cc = fr[2];
        float d = fr[3], e = fr[4], f5 = fr[5];
        float g7 = fr[6], h7 = fr[7], i8 = fr[8];

        // fr dead -> prefetch next F directly into fr (hides HBM latency)
        const bool havenext = (it + 1 < iters) && (ws + 64 < n);
        if (havenext) {
            long long sE = ws + 64 + l; if (sE > n - 1) sE = n - 1;
            const float* fp = Fs + sE * 9;
            #pragma unroll
            for (int q = 0; q < 9; ++q) fr[q] = fp[q];
        }

        // ---- features (f32): F(9), cofactor(9), det ----
        float C00 = e * i8 - f5 * h7;
        float C01 = f5 * g7 - d * i8;
        float C02 = d * h7 - e * g7;
        float det = fmaf(a, C00, fmaf(b, C01, cc * C02));
        float C10 = cc * h7 - b * i8;
        float C11 = a * i8 - cc * g7;
        float C12 = b * g7 - a * h7;
        float C20 = b * f5 - cc * e;
        float C21 = cc * d - a * f5;
        float C22 = a * e - b * d;

        {
            uint2 v;
            v.x = pk2(a,   b);   v.y = pk2(cc,  d);   basep[l*5 + 0] = v;
            v.x = pk2(e,   f5);  v.y = pk2(g7,  h7);  basep[l*5 + 1] = v;
            v.x = pk2(i8,  C00); v.y = pk2(C01, C02); basep[l*5 + 2] = v;
            v.x = pk2(C10, C11); v.y = pk2(C12, C20); basep[l*5 + 3] = v;
            v.x = pk2(C21, C22); v.y = pk2(det, 0.0f); basep[l*5 + 4] = v;
        }
        asm volatile("s_waitcnt lgkmcnt(0)" ::: "memory");

        // ---- two sequential halves: tiles {M0,M1} full chain + store ----
        // Halved live state (2 acc chains) aims VGPR <= 64 -> 8 waves/SIMD.
        #define HALF(M0, M1)                                                        \
        do {                                                                        \
            uint2 rlo0 = basep[(16*(M0) + c)*5 + g];                                \
            uint2 rlo1 = basep[(16*(M1) + c)*5 + g];                                \
            uint2 rhi0 = basep[(16*(M0) + c)*5 + 4];                                \
            uint2 rhi1 = basep[(16*(M1) + c)*5 + 4];                                \
            f32x4 t0 = __builtin_amdgcn_mfma_f32_16x16x32_f16(a1, h8(rlo0, rhi0), cb1, 0, 0, 0); \
            f32x4 t1 = __builtin_amdgcn_mfma_f32_16x16x32_f16(a1, h8(rlo1, rhi1), cb1, 0, 0, 0); \
            uint2 u0, u1;                                                           \
            u0.x = sp2_any(t0[0], t0[1]); u0.y = sp2_any(t0[2], t0[3]);             \
            u1.x = sp2_any(t1[0], t1[1]); u1.y = sp2_any(t1[2], t1[3]);             \
            t0 = __builtin_amdgcn_mfma_f32_16x16x16f16(a2, h4(u0), cb2, 0, 0, 0);   \
            t1 = __builtin_amdgcn_mfma_f32_16x16x16f16(a2, h4(u1), cb2, 0, 0, 0);   \
            u0.x = sp2_pos(t0[0], t0[1]); u0.y = sp2_pos(t0[2], t0[3]);             \
            u1.x = sp2_pos(t1[0], t1[1]); u1.y = sp2_pos(t1[2], t1[3]);             \
            t0 = __builtin_amdgcn_mfma_f32_16x16x16f16(a3, h4(u0), cb3, 0, 0, 0);   \
            t1 = __builtin_amdgcn_mfma_f32_16x16x16f16(a3, h4(u1), cb3, 0, 0, 0);   \
            u0.x = sp2_pos(t0[0], t0[1]); u0.y = sp2_pos(t0[2], t0[3]);             \
            u1.x = sp2_pos(t1[0], t1[1]); u1.y = sp2_pos(t1[2], t1[3]);             \
            t0 = __builtin_amdgcn_mfma_f32_16x16x16f16(a4, h4(u0), zero4, 0, 0, 0); \
            t1 = __builtin_amdgcn_mfma_f32_16x16x16f16(a4, h4(u1), zero4, 0, 0, 0); \
            float yo = (g == (M0)) ? t0[0] : t1[0];                                 \
            if ((g == (M0) || g == (M1)) && (ws + l < n)) out[ws + l] = yo + b4s;   \
        } while (0)

        HALF(0, 1);
        HALF(2, 3);
        #undef HALF
    }
}

extern "C" void kernel_launch(void* const* d_in, const int* in_sizes, int n_in,
                              void* d_out, int out_size, void* d_ws, size_t ws_size,
                              hipStream_t stream) {
    const float* Fs = (const float*)d_in[0];
    const float* W1 = (const float*)d_in[1];
    const float* b1 = (const float*)d_in[2];
    const float* W2 = (const float*)d_in[3];
    const float* b2 = (const float*)d_in[4];
    const float* W3 = (const float*)d_in[5];
    const float* b3 = (const float*)d_in[6];
    const float* W4 = (const float*)d_in[7];
    const float* b4 = (const float*)d_in[8];
    float* out = (float*)d_out;

    int n = in_sizes[0] / 9;
    int waves = (n + 63) / 64;
    int iters = (waves + BLOCKS * 4 - 1) / (BLOCKS * 4);
    mlp_mfma_kernel<<<BLOCKS, TPB, 0, stream>>>(Fs, W1, b1, W2, b2, W3, b3, W4, b4,
                                                out, n, iters);
}